// Round 6
// baseline (178.931 us; speedup 1.0000x reference)
//
#include <hip/hip_runtime.h>
#include <stdint.h>

#define ALPHA_C 1000.0f
#define EPS_C 1e-6f
#define NPTS 8192
#define BATCH 4
#define CLOUDS 8
#define G 16                 // grid cells per axis; G^3 = 4096 cells/cloud
#define NC 4096
#define CAP 8                // slots per cell (lambda=2; overflow list backs it)
#define OVFCAP 256
#define TOTQ 65536
#define TPB 256
#define QBLOCKS (TOTQ / TPB) // 256

// ws byte layout:
//   [0,       131072)  cellcnt  u32 [CLOUDS][NC]
//   [131072,  393216)  counts   u32 [CLOUDS][NPTS]
//   [393216,  655360)  expsum   f32 [CLOUDS][NPTS]
//   [655360]           ovf_cnt  u32
//   [655364]           done     u32
//   [655376,  659472)  ovf      float4[OVFCAP]   (x,y,z, idx|cloud<<16)
//   [659472, 4853776)  cells    float4[CLOUDS*NC*CAP] (x,y,z, idx)
#define OFF_COUNTS 131072
#define OFF_EXPSUM 393216
#define OFF_OVFCNT 655360
#define OFF_DONE 655364
#define OFF_OVF 655376
#define OFF_CELLS 659472

// ---------------------------------------------------------------------------
// zero_kernel: zero cellcnt+counts+expsum (163840 words) + ovf_cnt + done.
// ---------------------------------------------------------------------------
__global__ __launch_bounds__(TPB) void zero_kernel(uint4* __restrict__ w,
                                                   unsigned int* __restrict__ tail) {
  int i = blockIdx.x * TPB + threadIdx.x;           // 160*256 = 40960 uint4
  w[i] = (uint4){0u, 0u, 0u, 0u};
  if (i == 0) { tail[0] = 0u; tail[1] = 0u; }       // ovf_cnt, done
}

// ---------------------------------------------------------------------------
// bin_kernel: scatter all 8 clouds into the cell table (atomic slot claim);
// overflow (slot >= CAP) goes to a global list scanned by every query.
// ---------------------------------------------------------------------------
__global__ __launch_bounds__(TPB) void bin_kernel(
    const float* __restrict__ x, const float* __restrict__ y,
    unsigned int* __restrict__ cellcnt, float4* __restrict__ cells,
    unsigned int* __restrict__ ovf_cnt, float4* __restrict__ ovf) {
  int i = blockIdx.x * TPB + threadIdx.x;  // 0..TOTQ-1
  int cloud = i >> 13;                     // 0..3 = x batches, 4..7 = y batches
  int pidx = i & (NPTS - 1);
  const float* p =
      (cloud < 4 ? x + cloud * NPTS * 3 : y + (cloud - 4) * NPTS * 3) +
      pidx * 3;
  float px = p[0], py = p[1], pz = p[2];
  int cx = min(max((int)(px * (float)G), 0), G - 1);
  int cy = min(max((int)(py * (float)G), 0), G - 1);
  int cz = min(max((int)(pz * (float)G), 0), G - 1);
  int cell = (cz * G + cy) * G + cx;
  unsigned int slot = atomicAdd(cellcnt + (cloud << 12) + cell, 1u);
  if (slot < CAP) {
    cells[(((size_t)cloud << 12) + cell) * CAP + slot] =
        (float4){px, py, pz, __uint_as_float((unsigned int)pidx)};
  } else {
    unsigned int o = atomicAdd(ovf_cnt, 1u);
    if (o < OVFCAP)
      ovf[o] = (float4){px, py, pz,
                        __uint_as_float((unsigned int)(pidx | (cloud << 16)))};
  }
}

// ---------------------------------------------------------------------------
// query_kernel: exact NN via expanding cell-box search; exact reference-order
// d; exp/count scatter; done-counter last block reduces and writes out.
// ---------------------------------------------------------------------------
__global__ __launch_bounds__(TPB) void query_kernel(
    const float* __restrict__ x, const float* __restrict__ y,
    const unsigned int* __restrict__ cellcnt, const float4* __restrict__ cells,
    const unsigned int* __restrict__ ovf_cnt, const float4* __restrict__ ovf,
    unsigned int* __restrict__ counts, float* __restrict__ expsum,
    unsigned int* __restrict__ done, float* __restrict__ out) {
  int i = blockIdx.x * TPB + threadIdx.x;
  int q = i & (NPTS - 1);
  int db = i >> 13;  // dir*4 + b
  int b = db & (BATCH - 1);
  int dir = db >> 2;
  const float* qp = (dir == 0 ? x : y) + b * NPTS * 3;
  int ccloud = (dir == 0) ? (4 + b) : b;  // candidate cloud

  float qx = qp[q * 3 + 0], qy = qp[q * 3 + 1], qz = qp[q * 3 + 2];
  float xx = __fadd_rn(__fadd_rn(__fmul_rn(qx, qx), __fmul_rn(qy, qy)),
                       __fmul_rn(qz, qz));
  int cx = min(max((int)(qx * (float)G), 0), G - 1);
  int cy = min(max((int)(qy * (float)G), 0), G - 1);
  int cz = min(max((int)(qz * (float)G), 0), G - 1);

  const unsigned int* cc = cellcnt + (ccloud << 12);
  const float4* cl = cells + (((size_t)ccloud << 12) * CAP);

  unsigned long long bkey = ~0ull;

#define EVAL(PX, PY, PZ, IDX)                                                  \
  {                                                                            \
    float yy = __fadd_rn(                                                      \
        __fadd_rn(__fmul_rn(PX, PX), __fmul_rn(PY, PY)), __fmul_rn(PZ, PZ));   \
    float xy = __fadd_rn(                                                      \
        __fadd_rn(__fmul_rn(qx, PX), __fmul_rn(qy, PY)), __fmul_rn(qz, PZ));   \
    float d = __fadd_rn(__fsub_rn(xx, __fmul_rn(2.0f, xy)), yy);               \
    unsigned int sb = __float_as_uint(d);                                      \
    sb ^= ((unsigned int)((int)sb >> 31)) | 0x80000000u;                       \
    unsigned long long k =                                                     \
        ((unsigned long long)sb << 32) | (unsigned long long)(IDX);            \
    if (k < bkey) bkey = k;                                                    \
  }

  // overflow candidates (expected ~10 entries total; exactness backstop)
  {
    unsigned int no = *ovf_cnt;
    if (no > OVFCAP) no = OVFCAP;
    for (unsigned int j = 0; j < no; j++) {
      float4 p = ovf[j];
      unsigned int tag = __float_as_uint(p.w);
      if ((int)(tag >> 16) != ccloud) continue;
      EVAL(p.x, p.y, p.z, tag & 0xFFFFu);
    }
  }

  const float h = 1.0f / (float)G;
  for (int r = 1; r < G; r++) {
    int x0 = max(cx - r, 0), x1 = min(cx + r, G - 1);
    int y0 = max(cy - r, 0), y1 = min(cy + r, G - 1);
    int z0 = max(cz - r, 0), z1 = min(cz + r, G - 1);
    for (int zc = z0; zc <= z1; zc++)
      for (int yc = y0; yc <= y1; yc++) {
        int cid = (zc * G + yc) * G + x0;
        for (int xc = x0; xc <= x1; xc++, cid++) {
          unsigned int n = cc[cid];
          if (n > CAP) n = CAP;
          const float4* sp = cl + (size_t)cid * CAP;
          for (unsigned int s = 0; s < n; s++) {
            float4 p = sp[s];
            EVAL(p.x, p.y, p.z, __float_as_uint(p.w));
          }
        }
      }
    // exact-termination margin: distance from q to searched-box boundary
    // (clamped faces have no points beyond them -> infinite margin)
    float m = 1e30f;
    if (cx - r > 0) m = fminf(m, qx - (float)(cx - r) * h);
    if (cx + r < G - 1) m = fminf(m, (float)(cx + r + 1) * h - qx);
    if (cy - r > 0) m = fminf(m, qy - (float)(cy - r) * h);
    if (cy + r < G - 1) m = fminf(m, (float)(cy + r + 1) * h - qy);
    if (cz - r > 0) m = fminf(m, qz - (float)(cz - r) * h);
    if (cz + r < G - 1) m = fminf(m, (float)(cz + r + 1) * h - qz);
    if (bkey != ~0ull) {
      unsigned int sb = (unsigned int)(bkey >> 32);
      unsigned int ob = (sb & 0x80000000u) ? (sb ^ 0x80000000u) : ~sb;
      float bd = __uint_as_float(ob);
      if (m >= 1e29f || bd <= m * m) break;
    } else if (m >= 1e29f) {
      break;  // searched everything (cannot happen with non-empty clouds)
    }
  }

  // decode winner
  unsigned int idx = (unsigned int)(bkey & 0xFFFFu);
  unsigned int sb = (unsigned int)(bkey >> 32);
  unsigned int ob = (sb & 0x80000000u) ? (sb ^ 0x80000000u) : ~sb;
  float d = __uint_as_float(ob);

  int base = db << 13;
  atomicAdd(expsum + base + idx, expf(-d * ALPHA_C));
  atomicAdd(counts + base + idx, 1u);

  // last-block final reduction: total = sum_c expsum[c]/(cnt[c]+eps)
  __shared__ bool amLast;
  __shared__ float red[TPB];
  __threadfence();
  __syncthreads();
  if (threadIdx.x == 0) amLast = (atomicAdd(done, 1u) == QBLOCKS - 1);
  __syncthreads();
  if (amLast) {
    __threadfence();  // acquire; L1 invalidate before plain loads
    const float4* ev = (const float4*)expsum;
    const uint4* cv = (const uint4*)counts;
    float v = 0.0f;
    for (int j = threadIdx.x; j < TOTQ / 4; j += TPB) {
      float4 e = ev[j];
      uint4 c = cv[j];
      v += e.x / ((float)c.x + EPS_C) + e.y / ((float)c.y + EPS_C) +
           e.z / ((float)c.z + EPS_C) + e.w / ((float)c.w + EPS_C);
    }
    red[threadIdx.x] = v;
    __syncthreads();
    for (int s2 = TPB / 2; s2 > 0; s2 >>= 1) {
      if (threadIdx.x < s2) red[threadIdx.x] += red[threadIdx.x + s2];
      __syncthreads();
    }
    if (threadIdx.x == 0)
      out[0] = 1.0f - red[0] * (1.0f / (float)TOTQ);
  }
#undef EVAL
}

extern "C" void kernel_launch(void* const* d_in, const int* in_sizes, int n_in,
                              void* d_out, int out_size, void* d_ws,
                              size_t ws_size, hipStream_t stream) {
  const float* x = (const float*)d_in[0];
  const float* y = (const float*)d_in[1];
  float* out = (float*)d_out;

  char* p = (char*)d_ws;
  unsigned int* cellcnt = (unsigned int*)p;
  unsigned int* counts = (unsigned int*)(p + OFF_COUNTS);
  float* expsum = (float*)(p + OFF_EXPSUM);
  unsigned int* ovf_cnt = (unsigned int*)(p + OFF_OVFCNT);
  unsigned int* done = (unsigned int*)(p + OFF_DONE);
  float4* ovf = (float4*)(p + OFF_OVF);
  float4* cells = (float4*)(p + OFF_CELLS);

  zero_kernel<<<160, TPB, 0, stream>>>((uint4*)p, ovf_cnt);
  bin_kernel<<<TOTQ / TPB, TPB, 0, stream>>>(x, y, cellcnt, cells, ovf_cnt,
                                             ovf);
  query_kernel<<<QBLOCKS, TPB, 0, stream>>>(x, y, cellcnt, cells, ovf_cnt, ovf,
                                            counts, expsum, done, out);
}